// Round 1
// baseline (77.614 us; speedup 1.0000x reference)
//
#include <hip/hip_runtime.h>

// counts[b,s] = #{t <= s : x[b,t] == x[b,s]}  (inclusive), B=4, S=4096.
// R5: the key stream is wave-uniform (each wave scans a contiguous slice),
// so move it off the LDS/vector path onto the SCALAR pipe: wave id made
// provably uniform via readfirstlane -> key addresses are scalar ->
// s_load_dwordx4 through K$/L2 (input is only 64 KB, fully cached).
// Inner loop is then pure VALU: v_cmp_eq_u32 vcc, sK, vq + addc,
// ~4 cyc/key/wave. No 16 KB prefix staging, no staging __syncthreads;
// LDS only holds the 1 KB partial sums. Grid unchanged: (qt 0..63, b 0..3)
// = 256 blocks, one per CU, 256 threads = 4 wave-slices x 64 queries.

#define SEQ 4096
#define QT  64    // queries per block

__global__ __launch_bounds__(256)
void count_kernel(const int* __restrict__ x, float* __restrict__ out) {
    const int qt  = blockIdx.x;          // query tile 0..63
    const int b   = blockIdx.y;          // batch row
    const int tid = threadIdx.x;
    const int q   = tid & 63;            // query lane
    // wave id, made explicitly wave-uniform so all key-address math lands
    // in SGPRs and the key loads select the scalar (SMEM) path.
    const int g   = __builtin_amdgcn_readfirstlane(tid >> 6);

    const int* __restrict__ row = x + b * SEQ;
    const int4* __restrict__ kp = reinterpret_cast<const int4*>(row);

    const int s    = (qt << 6) + q;
    const int qval = row[s];             // per-lane coalesced vector load

    // full region: t in [0, qt*64) = qt*16 int4s; wave g scans
    // int4 indices [g*4*qt, (g+1)*4*qt)  -- uniform per wave
    int cnt = 0;
    const int lo = g * (qt << 2);
    const int hi = lo + (qt << 2);
    #pragma unroll 8
    for (int j = lo; j < hi; ++j) {
        const int4 a = kp[j];            // wave-uniform -> s_load_dwordx4
        cnt += (qval == a.x) + (qval == a.y) + (qval == a.z) + (qval == a.w);
    }

    // diagonal tile: t = qt*64 + k, k in [g*16, (g+1)*16), qualifies iff k <= q
    const int dbase = qt << 4;           // int4 index of diagonal start
    #pragma unroll
    for (int jj = 0; jj < 4; ++jj) {
        const int k = (g << 4) + (jj << 2);     // local element index
        const int4 a = kp[dbase + (k >> 2)];    // wave-uniform -> s_load
        cnt += (int)((k + 0 <= q) & (qval == a.x))
             + (int)((k + 1 <= q) & (qval == a.y))
             + (int)((k + 2 <= q) & (qval == a.z))
             + (int)((k + 3 <= q) & (qval == a.w));
    }

    __shared__ int partial[4][QT];
    partial[g][q] = cnt;
    __syncthreads();

    if (tid < QT) {
        const int tot = partial[0][tid] + partial[1][tid]
                      + partial[2][tid] + partial[3][tid];
        out[b * SEQ + (qt << 6) + tid] = (float)tot;
    }
}

extern "C" void kernel_launch(void* const* d_in, const int* in_sizes, int n_in,
                              void* d_out, int out_size, void* d_ws, size_t ws_size,
                              hipStream_t stream) {
    const int* x = (const int*)d_in[0];
    float* out = (float*)d_out;
    const int B = in_sizes[0] / SEQ;   // 4

    count_kernel<<<dim3(SEQ / QT, B), 256, 0, stream>>>(x, out);
}

// Round 2
// 59.856 us; speedup vs baseline: 1.2967x; 1.2967x over previous
//
#include <hip/hip_runtime.h>

// counts[b,s] = #{t <= s : x[b,t] == x[b,s]}  (inclusive), B=4, S=4096.
// R6: revert R5's scalar-pipe experiment (regressed: SMEM loads serialize on
// conservative lgkmcnt(0) waits; LDS broadcast + compiler-batched lgkmcnt(N)
// was the right pipe). Keep the proven structure, add latency hiding:
// 512 threads = 8 waves = 2 waves/SIMD (was 1), so ds_read latency overlaps
// across co-resident waves. Same per-SIMD instruction count, dual
// accumulators to shorten the add chain. Staging is 2 int4/thread (trivial).
// Grid (qt 0..63, b 0..3) = 256 blocks, one per CU.

#define SEQ 4096
#define QT  64    // queries per block
#define SL  8     // t-slices = waves per block

__global__ __launch_bounds__(SL * 64)
void count_kernel(const int* __restrict__ x, float* __restrict__ out) {
    const int qt  = blockIdx.x;          // query tile 0..63
    const int b   = blockIdx.y;          // batch row
    const int tid = threadIdx.x;
    const int q   = tid & 63;            // query lane
    const int g   = tid >> 6;            // t-slice / wave id 0..7
    const int* __restrict__ row = x + b * SEQ;

    __shared__ int prefix[SEQ];          // 16 KB max
    __shared__ int partial[SL][QT];      // 2 KB

    // stage the whole prefix [0, (qt+1)*64) once, coalesced int4
    const int end_i4 = (qt + 1) * (QT / 4);   // (qt+1)*16 int4s
    for (int j = tid; j < end_i4; j += SL * 64)
        reinterpret_cast<int4*>(prefix)[j] =
            reinterpret_cast<const int4*>(row)[j];
    __syncthreads();

    const int s    = (qt << 6) + q;
    const int qval = prefix[s];

    // full region: t in [0, qt*64) = qt*16 int4s; wave g scans
    // int4 indices [g*2*qt, (g+1)*2*qt)  -- per = qt*2 is always even
    int c0 = 0, c1 = 0;
    const int per = qt * (16 / SL);      // int4s per wave
    const int lo  = g * per;
    const int hi  = lo + per;
    #pragma unroll 4
    for (int j = lo; j < hi; j += 2) {   // 2 streams for ILP
        const int4 a  = reinterpret_cast<const int4*>(prefix)[j];
        const int4 a2 = reinterpret_cast<const int4*>(prefix)[j + 1];
        c0 += (qval == a.x)  + (qval == a.y)  + (qval == a.z)  + (qval == a.w);
        c1 += (qval == a2.x) + (qval == a2.y) + (qval == a2.z) + (qval == a2.w);
    }

    // diagonal tile: t = qt*64 + k, k in [g*8, (g+1)*8), qualifies iff k <= q
    const int dbase = qt << 4;           // int4 index of diagonal start
    #pragma unroll
    for (int jj = 0; jj < 2; ++jj) {
        const int k = (g << 3) + (jj << 2);     // local element index
        const int4 a = reinterpret_cast<const int4*>(prefix)[dbase + (k >> 2)];
        c0 += (int)((k + 0 <= q) & (qval == a.x))
            + (int)((k + 1 <= q) & (qval == a.y))
            + (int)((k + 2 <= q) & (qval == a.z))
            + (int)((k + 3 <= q) & (qval == a.w));
    }

    partial[g][q] = c0 + c1;
    __syncthreads();

    // partial[w][tid]: stride 64 ints between w -> bank = tid%32, conflict-free
    if (tid < QT) {
        int tot = 0;
        #pragma unroll
        for (int w = 0; w < SL; ++w) tot += partial[w][tid];
        out[b * SEQ + (qt << 6) + tid] = (float)tot;
    }
}

extern "C" void kernel_launch(void* const* d_in, const int* in_sizes, int n_in,
                              void* d_out, int out_size, void* d_ws, size_t ws_size,
                              hipStream_t stream) {
    const int* x = (const int*)d_in[0];
    float* out = (float*)d_out;
    const int B = in_sizes[0] / SEQ;   // 4

    count_kernel<<<dim3(SEQ / QT, B), SL * 64, 0, stream>>>(x, out);
}